// Round 14
// baseline (504.969 us; speedup 1.0000x reference)
//
#include <hip/hip_runtime.h>
#include <math.h>

// PhaseRefinement fused kernel, v14 = v13 with the nontemporal builtin type
// fixed (needs native clang ext_vector_type, not HIP_vector_type).
// Model (v11/v12 evidence): wall is the per-CU vector-memory/L2 path at
// ~29 B/cyc effective. Dominant term: 8x redundant x reads -- all 8 waves
// load the same 8 rows per chunk, and the 32KB of distinct per-wave W
// streaming through L1 evicts x, so all 8 copies go to L2. Fix without
// touching the proven structure (VGPR<=64 keeps the 43% occupancy tier --
// v12 showed VGPR>64 costs the 64-VGPR cliff):
//  1. W loads non-temporal (no L1 allocation) -> x lines stay resident;
//  2. one RAW s_barrier per chunk (no vmcnt drain, unlike __syncthreads):
//     keeps the 8 waves in the same 8KB x-window -> ~7/8 x loads L1-hit;
//  3. nt stores for out (never re-read).
//
// out = x + LN(c*x)*gamma + beta; LN(c*x) collapses to
//   normed = gamma*(alpha*x - alpha*mu) + beta,
//   alpha = c*rsqrt(c^2*var + 1e-5), mu/var = plain row stats of x.

constexpr int Dh     = 4096;
constexpr int Ph     = 16;
constexpr int NPL    = 32;          // 2*P dots per row
constexpr int CHUNK  = 256;         // 64 lanes * 4 floats
constexpr int NCHUNK = Dh / CHUNK;  // 16
constexpr int RPB    = 8;           // rows per block
constexpr int NW     = 8;           // waves per block
constexpr int PPW    = NPL / NW;    // 4 planes per wave
constexpr int BLOCK  = 64 * NW;     // 512

typedef float float4n __attribute__((ext_vector_type(4)));  // builtin-legal

// saddr form: block-uniform base in SGPR pair + shared 32-bit per-lane
// byte offset VGPR. Volatile => program-ordered; proven codegen (v11).
__device__ __forceinline__ float4 gload_s(const float* sbase, int voff) {
    float4 v;
    asm volatile("global_load_dwordx4 %0, %1, %2"
                 : "=v"(v) : "v"(voff), "s"(sbase));
    return v;
}

__global__ __launch_bounds__(BLOCK, 2)
void phase_fused(const float* __restrict__ x,
                 const float* __restrict__ Wr,
                 const float* __restrict__ br,
                 const float* __restrict__ Wo,
                 const float* __restrict__ bo,
                 const float* __restrict__ gamma,
                 const float* __restrict__ beta,
                 float* __restrict__ out)
{
    __shared__ float dots_lds[RPB][NPL];
    __shared__ float stats_lds[RPB][2];
    __shared__ float scale_lds[RPB][2];

    const int t    = threadIdx.x;
    const int wv   = t >> 6;
    const int lane = t & 63;
    const size_t rowbase = (size_t)blockIdx.x * RPB;

    // Block-uniform x bases (no lane offset -> SGPR pairs for saddr form).
    const float* xbase[RPB];
#pragma unroll
    for (int r = 0; r < RPB; ++r)
        xbase[r] = x + (rowbase + r) * (size_t)Dh;

    // Per-wave W pointers (lane offset folded in; advanced per chunk).
    const float* wptr[PPW];
#pragma unroll
    for (int p = 0; p < PPW; ++p) {
        const int q = wv * PPW + p;
        wptr[p] = ((q < Ph) ? (Wr + (size_t)q * Dh) : (Wo + (size_t)(q - Ph) * Dh))
                  + lane * 4;
    }

    float acc[RPB][PPW];
#pragma unroll
    for (int r = 0; r < RPB; ++r)
#pragma unroll
        for (int p = 0; p < PPW; ++p) acc[r][p] = 0.f;
    float sx = 0.f, sxx = 0.f;

    int voff = lane * 16;              // per-lane byte offset, +1024/chunk
#pragma unroll 1
    for (int c = 0; c < NCHUNK; ++c) {
        // Raw barrier: timing cohesion only (no memory semantics needed --
        // no LDS data exchanged in the loop). Keeps all 8 waves inside the
        // same 8KB x window so x lines are shared in L1.
        __builtin_amdgcn_s_barrier();

        // 8 ordered asm x loads (L1-cached; shared across the block's waves).
        float4 x4[RPB];
#pragma unroll
        for (int r = 0; r < RPB; ++r)
            x4[r] = gload_s(xbase[r], voff);
        // 4 W loads, NON-TEMPORAL: stream past L1, don't evict x.
        float4n w4[PPW];
#pragma unroll
        for (int p = 0; p < PPW; ++p)
            w4[p] = __builtin_nontemporal_load(
                        reinterpret_cast<const float4n*>(wptr[p]));

        asm volatile("s_waitcnt vmcnt(0)" ::: "memory");
        __builtin_amdgcn_sched_barrier(0);   // rule #18: no consumer hoisting

#pragma unroll
        for (int r = 0; r < RPB; ++r) {
            if (r == wv) {   // wave-uniform; static indices
                sx  += x4[r].x + x4[r].y + x4[r].z + x4[r].w;
                sxx += x4[r].x*x4[r].x + x4[r].y*x4[r].y
                     + x4[r].z*x4[r].z + x4[r].w*x4[r].w;
            }
#pragma unroll
            for (int p = 0; p < PPW; ++p)
                acc[r][p] += x4[r].x*w4[p].x + x4[r].y*w4[p].y
                           + x4[r].z*w4[p].z + x4[r].w*w4[p].w;
        }
        voff += CHUNK * 4;
#pragma unroll
        for (int p = 0; p < PPW; ++p) wptr[p] += CHUNK;
    }

    // Butterfly-reduce accumulators across the 64 lanes.
#pragma unroll
    for (int r = 0; r < RPB; ++r)
#pragma unroll
        for (int p = 0; p < PPW; ++p) {
            float v = acc[r][p];
#pragma unroll
            for (int m = 1; m < 64; m <<= 1) v += __shfl_xor(v, m, 64);
            if (lane == 0) dots_lds[r][wv * PPW + p] = v;
        }
#pragma unroll
    for (int m = 1; m < 64; m <<= 1) {
        sx  += __shfl_xor(sx, m, 64);
        sxx += __shfl_xor(sxx, m, 64);
    }
    if (lane == 0) { stats_lds[wv][0] = sx; stats_lds[wv][1] = sxx; }
    __syncthreads();

    // Scalar phase, parallel over (row, plane): 128 threads, 16-lane reduce.
    if (t < RPB * Ph) {
        const int r = t >> 4, p = t & 15;
        float d1 = dots_lds[r][p]      + br[p];
        float d2 = dots_lds[r][Ph + p] + bo[p];
        float cd = cosf((tanhf(d1) - tanhf(d2)) * 3.14159265358979323846f);
#pragma unroll
        for (int m = 1; m < 16; m <<= 1) cd += __shfl_xor(cd, m, 16);
        if (p == 0) {
            float s    = cd;
            float gain = log1pf(expf(s * (1.f / Ph) + 0.5f));  // softplus
            float cm   = s * gain * (1.f / Ph);
            float mu   = stats_lds[r][0] * (1.f / Dh);
            float var  = stats_lds[r][1] * (1.f / Dh) - mu * mu;
            var = fmaxf(var, 0.f);
            float rstd  = rsqrtf(cm * cm * var + 1e-5f);
            float alpha = cm * rstd;
            scale_lds[r][0] = alpha;
            scale_lds[r][1] = alpha * mu;
        }
    }
    __syncthreads();

    // Phase B, column-sliced: wave wv owns cols [wv*512, wv*512+512);
    // gamma/beta loaded ONCE per wave, reused across all 8 rows. x re-read
    // is L2-hot; out stores non-temporal (never re-read).
    {
        const int col0 = wv * 512 + lane * 4;
        const float4 g4a = *(const float4*)(gamma + col0);
        const float4 g4b = *(const float4*)(gamma + col0 + 256);
        const float4 b4a = *(const float4*)(beta  + col0);
        const float4 b4b = *(const float4*)(beta  + col0 + 256);
#pragma unroll
        for (int r = 0; r < RPB; ++r) {
            const float alpha = scale_lds[r][0];
            const float am    = scale_lds[r][1];
            const float* xr  = x   + (rowbase + r) * (size_t)Dh;
            float*       orw = out + (rowbase + r) * (size_t)Dh;
            float4 xa = *(const float4*)(xr + col0);
            float4 xb = *(const float4*)(xr + col0 + 256);
            float4n oa, ob;
            oa.x = xa.x + g4a.x * (alpha * xa.x - am) + b4a.x;
            oa.y = xa.y + g4a.y * (alpha * xa.y - am) + b4a.y;
            oa.z = xa.z + g4a.z * (alpha * xa.z - am) + b4a.z;
            oa.w = xa.w + g4a.w * (alpha * xa.w - am) + b4a.w;
            ob.x = xb.x + g4b.x * (alpha * xb.x - am) + b4b.x;
            ob.y = xb.y + g4b.y * (alpha * xb.y - am) + b4b.y;
            ob.z = xb.z + g4b.z * (alpha * xb.z - am) + b4b.z;
            ob.w = xb.w + g4b.w * (alpha * xb.w - am) + b4b.w;
            __builtin_nontemporal_store(oa, reinterpret_cast<float4n*>(orw + col0));
            __builtin_nontemporal_store(ob, reinterpret_cast<float4n*>(orw + col0 + 256));
        }
    }
}

extern "C" void kernel_launch(void* const* d_in, const int* in_sizes, int n_in,
                              void* d_out, int out_size, void* d_ws, size_t ws_size,
                              hipStream_t stream)
{
    const float* x     = (const float*)d_in[0];
    const float* Wr    = (const float*)d_in[1];
    const float* br    = (const float*)d_in[2];
    const float* Wo    = (const float*)d_in[3];
    const float* bo    = (const float*)d_in[4];
    const float* gamma = (const float*)d_in[5];
    const float* beta  = (const float*)d_in[6];
    float* out = (float*)d_out;

    const int B = in_sizes[0] / Dh;       // 32768
    dim3 grid(B / RPB);                   // 4096 blocks
    phase_fused<<<grid, BLOCK, 0, stream>>>(x, Wr, br, Wo, bo, gamma, beta, out);
}

// Round 15
// 353.878 us; speedup vs baseline: 1.4270x; 1.4270x over previous
//
#include <hip/hip_runtime.h>
#include <math.h>

// PhaseRefinement fused kernel, v15: x through the LDS port.
// Model locked by R11/R12/R14: the wall is the L1 return port (64 B/cyc/CU).
// R11: 12 redundant loads/wave/chunk -> 2688 cyc L1 time vs 1120 VALU ->
// VALUBusy 42% predicted, 41% measured. Fix: move the 8x-redundant x reads
// to the LDS port (separate 128 B/cyc pipe). x staged once per block via
// global_load_lds; W stays on L1 (4 loads/wave/chunk). Port balance/chunk/
// block: L1 640, LDS 768, VALU ~600 -> 3.5x less port time than R11.
// LDS reads tolerate the 64-VGPR cap (12-cyc throughput hops, not 900-cyc
// global latency), so the 43-45% occupancy tier is preserved -- the reason
// every >64-VGPR design (R4/R6/R7/R9/R12) lost.
// vs R2 (474us, same idea at group=1): groups of 2 chunks -> compute/barrier
// ~900 cyc >= stage latency; barriers 17 -> 5; peeled const buffer indices.
//
// out = x + LN(c*x)*gamma + beta; LN(c*x) collapses to
//   normed = gamma*(alpha*x - alpha*mu) + beta,
//   alpha = c*rsqrt(c^2*var + 1e-5), mu/var = plain row stats of x.

constexpr int Dh     = 4096;
constexpr int Ph     = 16;
constexpr int NPL    = 32;
constexpr int CHUNK  = 256;           // 64 lanes * 4 floats
constexpr int GCH    = 2;             // chunks per group (512 cols)
constexpr int NGRP   = Dh / (CHUNK * GCH);   // 8
constexpr int RPB    = 8;             // rows per block
constexpr int NW     = 8;             // waves per block
constexpr int PPW    = NPL / NW;      // 4 planes per wave
constexpr int BLOCK  = 64 * NW;       // 512

__device__ __forceinline__ void stage_chunk(const float* src, float* ldsdst) {
    __builtin_amdgcn_global_load_lds(
        (const __attribute__((address_space(1))) void*)src,
        (__attribute__((address_space(3))) void*)ldsdst, 16, 0, 0);
}

__global__ __launch_bounds__(BLOCK, 4)
void phase_fused(const float* __restrict__ x,
                 const float* __restrict__ Wr,
                 const float* __restrict__ br,
                 const float* __restrict__ Wo,
                 const float* __restrict__ bo,
                 const float* __restrict__ gamma,
                 const float* __restrict__ beta,
                 float* __restrict__ out)
{
    __shared__ float x_lds[2][GCH][RPB][CHUNK];   // 32 KB double buffer
    __shared__ float dots_lds[RPB][NPL];
    __shared__ float stats_lds[RPB][2];
    __shared__ float scale_lds[RPB][2];

    const int t    = threadIdx.x;
    const int wv   = t >> 6;
    const int lane = t & 63;
    const size_t rowbase = (size_t)blockIdx.x * RPB;

    // Per-wave W pointers (lane offset folded in).
    const float* wrow[PPW];
#pragma unroll
    for (int p = 0; p < PPW; ++p) {
        const int q = wv * PPW + p;
        wrow[p] = ((q < Ph) ? (Wr + (size_t)q * Dh) : (Wo + (size_t)(q - Ph) * Dh))
                  + lane * 4;
    }
    // Wave wv stages row wv; global src per-lane, LDS dst wave-uniform linear.
    const float* xsrc = x + (rowbase + wv) * (size_t)Dh + lane * 4;

    float acc[RPB][PPW];
#pragma unroll
    for (int r = 0; r < RPB; ++r)
#pragma unroll
        for (int p = 0; p < PPW; ++p) acc[r][p] = 0.f;
    float sx = 0.f, sxx = 0.f;

    // Stage one 512-col group (2 chunks) of this wave's row into buf.
    auto stage_group = [&](int g, int buf) {
#pragma unroll
        for (int k = 0; k < GCH; ++k)
            stage_chunk(xsrc + (size_t)(g * GCH + k) * CHUNK,
                        &x_lds[buf][k][wv][0]);
    };

    // Compute one group from buf (const buf at every call site).
    auto compute_group = [&](int g, int buf) {
#pragma unroll 1
        for (int k = 0; k < GCH; ++k) {
            const int off = (g * GCH + k) * CHUNK;
            float4 w4[PPW];
#pragma unroll
            for (int p = 0; p < PPW; ++p)
                w4[p] = *(const float4*)(wrow[p] + off);
            float4 x4[RPB];
#pragma unroll
            for (int r = 0; r < RPB; ++r)
                x4[r] = *(const float4*)(&x_lds[buf][k][r][lane * 4]);

#pragma unroll
            for (int r = 0; r < RPB; ++r) {
                if (r == wv) {   // wave-uniform; static indices
                    sx  += x4[r].x + x4[r].y + x4[r].z + x4[r].w;
                    sxx += x4[r].x*x4[r].x + x4[r].y*x4[r].y
                         + x4[r].z*x4[r].z + x4[r].w*x4[r].w;
                }
#pragma unroll
                for (int p = 0; p < PPW; ++p)
                    acc[r][p] += x4[r].x*w4[p].x + x4[r].y*w4[p].y
                               + x4[r].z*w4[p].z + x4[r].w*w4[p].w;
            }
        }
    };

    // Software pipeline, 5 barriers total. compute(g) reads buf g&1 while
    // stage(g+1) fills the other; __syncthreads' vmcnt(0) drain is covered
    // by ~900 cyc of group compute (+ the co-resident block).
    stage_group(0, 0);
    __syncthreads();
    stage_group(1, 1); compute_group(0, 0);
    __syncthreads();
    stage_group(2, 0); compute_group(1, 1);
    __syncthreads();
    stage_group(3, 1); compute_group(2, 0);
    __syncthreads();
    stage_group(4, 0); compute_group(3, 1);
    __syncthreads();
    stage_group(5, 1); compute_group(4, 0);
    __syncthreads();
    stage_group(6, 0); compute_group(5, 1);
    __syncthreads();
    stage_group(7, 1); compute_group(6, 0);
    __syncthreads();
    compute_group(7, 1);

    // Butterfly-reduce accumulators across the 64 lanes.
#pragma unroll
    for (int r = 0; r < RPB; ++r)
#pragma unroll
        for (int p = 0; p < PPW; ++p) {
            float v = acc[r][p];
#pragma unroll
            for (int m = 1; m < 64; m <<= 1) v += __shfl_xor(v, m, 64);
            if (lane == 0) dots_lds[r][wv * PPW + p] = v;
        }
#pragma unroll
    for (int m = 1; m < 64; m <<= 1) {
        sx  += __shfl_xor(sx, m, 64);
        sxx += __shfl_xor(sxx, m, 64);
    }
    if (lane == 0) { stats_lds[wv][0] = sx; stats_lds[wv][1] = sxx; }
    __syncthreads();

    // Scalar phase, parallel over (row, plane): 128 threads, 16-lane reduce.
    if (t < RPB * Ph) {
        const int r = t >> 4, p = t & 15;
        float d1 = dots_lds[r][p]      + br[p];
        float d2 = dots_lds[r][Ph + p] + bo[p];
        float cd = cosf((tanhf(d1) - tanhf(d2)) * 3.14159265358979323846f);
#pragma unroll
        for (int m = 1; m < 16; m <<= 1) cd += __shfl_xor(cd, m, 16);
        if (p == 0) {
            float s    = cd;
            float gain = log1pf(expf(s * (1.f / Ph) + 0.5f));  // softplus
            float cm   = s * gain * (1.f / Ph);
            float mu   = stats_lds[r][0] * (1.f / Dh);
            float var  = stats_lds[r][1] * (1.f / Dh) - mu * mu;
            var = fmaxf(var, 0.f);
            float rstd  = rsqrtf(cm * cm * var + 1e-5f);
            float alpha = cm * rstd;
            scale_lds[r][0] = alpha;
            scale_lds[r][1] = alpha * mu;
        }
    }
    __syncthreads();

    // Phase B, column-sliced: wave wv owns cols [wv*512, wv*512+512);
    // gamma/beta loaded ONCE per wave, reused across all 8 rows. x re-read
    // is L2-hot (FETCH_SIZE ~= x-once at HBM every round).
    {
        const int col0 = wv * 512 + lane * 4;
        const float4 g4a = *(const float4*)(gamma + col0);
        const float4 g4b = *(const float4*)(gamma + col0 + 256);
        const float4 b4a = *(const float4*)(beta  + col0);
        const float4 b4b = *(const float4*)(beta  + col0 + 256);
#pragma unroll
        for (int r = 0; r < RPB; ++r) {
            const float alpha = scale_lds[r][0];
            const float am    = scale_lds[r][1];
            const float* xr  = x   + (rowbase + r) * (size_t)Dh;
            float*       orw = out + (rowbase + r) * (size_t)Dh;
            float4 xa = *(const float4*)(xr + col0);
            float4 xb = *(const float4*)(xr + col0 + 256);
            float4 oa, ob;
            oa.x = xa.x + g4a.x * (alpha * xa.x - am) + b4a.x;
            oa.y = xa.y + g4a.y * (alpha * xa.y - am) + b4a.y;
            oa.z = xa.z + g4a.z * (alpha * xa.z - am) + b4a.z;
            oa.w = xa.w + g4a.w * (alpha * xa.w - am) + b4a.w;
            ob.x = xb.x + g4b.x * (alpha * xb.x - am) + b4b.x;
            ob.y = xb.y + g4b.y * (alpha * xb.y - am) + b4b.y;
            ob.z = xb.z + g4b.z * (alpha * xb.z - am) + b4b.z;
            ob.w = xb.w + g4b.w * (alpha * xb.w - am) + b4b.w;
            *(float4*)(orw + col0)       = oa;
            *(float4*)(orw + col0 + 256) = ob;
        }
    }
}

extern "C" void kernel_launch(void* const* d_in, const int* in_sizes, int n_in,
                              void* d_out, int out_size, void* d_ws, size_t ws_size,
                              hipStream_t stream)
{
    const float* x     = (const float*)d_in[0];
    const float* Wr    = (const float*)d_in[1];
    const float* br    = (const float*)d_in[2];
    const float* Wo    = (const float*)d_in[3];
    const float* bo    = (const float*)d_in[4];
    const float* gamma = (const float*)d_in[5];
    const float* beta  = (const float*)d_in[6];
    float* out = (float*)d_out;

    const int B = in_sizes[0] / Dh;       // 32768
    dim3 grid(B / RPB);                   // 4096 blocks
    phase_fused<<<grid, BLOCK, 0, stream>>>(x, Wr, br, Wo, bo, gamma, beta, out);
}